// Round 2
// baseline (3160.884 us; speedup 1.0000x reference)
//
#include <hip/hip_runtime.h>
#include <hip/hip_bf16.h>

#define N_TOK 2048
#define H_DIM 4096
#define V_DIM 32000

typedef __attribute__((ext_vector_type(4))) float   f32x4;
typedef __attribute__((ext_vector_type(8))) short   short8_t;
typedef __attribute__((ext_vector_type(4))) short   short4_t;

static __device__ __forceinline__ short f2bf(float f) {
    __hip_bfloat16 b = __float2bfloat16(f);
    return __builtin_bit_cast(short, b);
}
static __device__ __forceinline__ float bf2f(short s) {
    unsigned u = ((unsigned)(unsigned short)s) << 16;
    return __builtin_bit_cast(float, u);
}

constexpr int BM  = 128;   // M and N tile
constexpr int BK  = 64;    // K tile
constexpr int NKT = H_DIM / BK;  // 64 K-steps

// ---------------------------------------------------------------------------
// GEMM: logits[b][n][v] = sum_h X_b[n][h] * W_b[v][h], stored as bf16.
// grid = 2 * (2048/128) * (32000/128) = 8000 blocks, 256 threads (4 waves).
// ---------------------------------------------------------------------------
__global__ __launch_bounds__(256, 2)
void gemm_logits_kernel(const float* __restrict__ Xs, const float* __restrict__ Xt,
                        const float* __restrict__ Ws, const float* __restrict__ Wt,
                        __hip_bfloat16* __restrict__ logits)
{
    __shared__ __align__(16) char ldsA[BM * BK * 2];   // 16 KiB bf16
    __shared__ __align__(16) char ldsB[BM * BK * 2];   // 16 KiB bf16

    // bijective XCD swizzle: nwg = 8000, 8 XCDs, q = 1000, r = 0
    int bid = blockIdx.x;
    int wg  = (bid & 7) * 1000 + (bid >> 3);
    int b   = wg / 4000;
    int rem = wg - b * 4000;
    int vtile = rem >> 4;    // 0..249  (consecutive wg share vtile -> W panel in XCD L2)
    int mtile = rem & 15;    // 0..15

    const float* X = b ? Xt : Xs;
    const float* W = b ? Wt : Ws;
    __hip_bfloat16* out = logits + (size_t)b * N_TOK * V_DIM;

    const int m0 = mtile * BM;
    const int v0 = vtile * BM;

    const int tid  = threadIdx.x;
    const int lane = tid & 63;
    const int wave = tid >> 6;
    const int wr   = wave >> 1;   // wave row (0..1), owns 64 output rows
    const int wc   = wave & 1;    // wave col (0..1), owns 64 output cols

    // staging map: pass p (0..7): row = p*16 + (tid>>4), float4 at col (tid&15)*4
    const int srow  = tid >> 4;         // 0..15
    const int scol  = (tid & 15) * 4;   // f32 element col
    const int scolb = (tid & 15) * 8;   // byte col in bf16 row (64 elems * 2B = 128B)
    const int sw    = (srow & 7) << 4;  // XOR swizzle (per-16B-granule)

    f32x4 aReg[8], bReg[8];

    auto loadRegs = [&](int kt) {
        const int k0 = kt * BK;
        #pragma unroll
        for (int p = 0; p < 8; ++p) {
            int row = p * 16 + srow;
            aReg[p] = *(const f32x4*)(X + (size_t)(m0 + row) * H_DIM + k0 + scol);
            bReg[p] = *(const f32x4*)(W + (size_t)(v0 + row) * H_DIM + k0 + scol);
        }
    };

    auto writeLDS = [&]() {
        #pragma unroll
        for (int p = 0; p < 8; ++p) {
            int row = p * 16 + srow;
            short4_t pa, pb;
            pa[0] = f2bf(aReg[p][0]); pa[1] = f2bf(aReg[p][1]);
            pa[2] = f2bf(aReg[p][2]); pa[3] = f2bf(aReg[p][3]);
            pb[0] = f2bf(bReg[p][0]); pb[1] = f2bf(bReg[p][1]);
            pb[2] = f2bf(bReg[p][2]); pb[3] = f2bf(bReg[p][3]);
            int off = row * 128 + (scolb ^ sw);
            *(short4_t*)(ldsA + off) = pa;
            *(short4_t*)(ldsB + off) = pb;
        }
    };

    f32x4 acc[4][4];
    #pragma unroll
    for (int i = 0; i < 4; ++i)
        #pragma unroll
        for (int j = 0; j < 4; ++j) {
            acc[i][j][0] = 0.f; acc[i][j][1] = 0.f; acc[i][j][2] = 0.f; acc[i][j][3] = 0.f;
        }

    loadRegs(0);

    #pragma unroll 1
    for (int kt = 0; kt < NKT; ++kt) {
        __syncthreads();            // previous compute done, LDS free
        writeLDS();
        __syncthreads();            // LDS tile ready
        if (kt + 1 < NKT) loadRegs(kt + 1);   // prefetch next tile's globals

        #pragma unroll
        for (int ks = 0; ks < 2; ++ks) {
            short8_t af[4], bq[4];
            #pragma unroll
            for (int i = 0; i < 4; ++i) {
                int row  = wr * 64 + i * 16 + (lane & 15);
                int gran = ks * 4 + (lane >> 4);
                int off  = row * 128 + ((gran * 16) ^ ((row & 7) << 4));
                af[i] = *(const short8_t*)(ldsA + off);
            }
            #pragma unroll
            for (int j = 0; j < 4; ++j) {
                int row  = wc * 64 + j * 16 + (lane & 15);
                int gran = ks * 4 + (lane >> 4);
                int off  = row * 128 + ((gran * 16) ^ ((row & 7) << 4));
                bq[j] = *(const short8_t*)(ldsB + off);
            }
            #pragma unroll
            for (int i = 0; i < 4; ++i)
                #pragma unroll
                for (int j = 0; j < 4; ++j)
                    acc[i][j] = __builtin_amdgcn_mfma_f32_16x16x32_bf16(af[i], bq[j], acc[i][j], 0, 0, 0);
        }
    }

    // epilogue: C/D layout (m89-verified): row = (lane>>4)*4 + reg, col = lane&15
    #pragma unroll
    for (int i = 0; i < 4; ++i) {
        #pragma unroll
        for (int j = 0; j < 4; ++j) {
            #pragma unroll
            for (int r = 0; r < 4; ++r) {
                int row = m0 + wr * 64 + i * 16 + ((lane >> 4) << 2) + r;
                int col = v0 + wc * 64 + j * 16 + (lane & 15);
                out[(size_t)row * V_DIM + col] = __float2bfloat16(acc[i][j][r]);
            }
        }
    }
}

// ---------------------------------------------------------------------------
// Per-row JSD: pass 1 sum(exp(logit)) -> lse (no max needed: |logit| <~ 4),
// pass 2 accumulate 0.5*[p*(lp-lm) + q*(lq-lm)].  One block per token.
// ---------------------------------------------------------------------------
__global__ __launch_bounds__(256)
void jsd_reduce_kernel(const __hip_bfloat16* __restrict__ logits,
                       const int* __restrict__ label,
                       float* __restrict__ loss_sum)
{
    const int n   = blockIdx.x;
    const int tid = threadIdx.x;
    const __hip_bfloat16* Ls = logits + (size_t)n * V_DIM;
    const __hip_bfloat16* Lt = logits + (size_t)(N_TOK + n) * V_DIM;

    __shared__ float sred[4];

    float ss = 0.f, st = 0.f;
    for (int v = tid * 8; v < V_DIM; v += 256 * 8) {
        short8_t s = *(const short8_t*)(Ls + v);
        short8_t t = *(const short8_t*)(Lt + v);
        #pragma unroll
        for (int j = 0; j < 8; ++j) {
            ss += __expf(bf2f(s[j]));
            st += __expf(bf2f(t[j]));
        }
    }
    // block reduce ss
    for (int d = 32; d; d >>= 1) ss += __shfl_down(ss, d);
    if ((tid & 63) == 0) sred[tid >> 6] = ss;
    __syncthreads();
    float SS = sred[0] + sred[1] + sred[2] + sred[3];
    __syncthreads();
    for (int d = 32; d; d >>= 1) st += __shfl_down(st, d);
    if ((tid & 63) == 0) sred[tid >> 6] = st;
    __syncthreads();
    float ST = sred[0] + sred[1] + sred[2] + sred[3];
    __syncthreads();

    const float lse_s = __logf(SS);
    const float lse_t = __logf(ST);

    float acc = 0.f;
    for (int v = tid * 8; v < V_DIM; v += 256 * 8) {
        short8_t s = *(const short8_t*)(Ls + v);
        short8_t t = *(const short8_t*)(Lt + v);
        #pragma unroll
        for (int j = 0; j < 8; ++j) {
            float lq = bf2f(s[j]) - lse_s;
            float lp = bf2f(t[j]) - lse_t;
            float q  = __expf(lq);
            float p  = __expf(lp);
            float m  = 0.5f * (p + q);
            float lm = __logf(m);
            acc += 0.5f * (p * (lp - lm) + q * (lq - lm));
        }
    }
    for (int d = 32; d; d >>= 1) acc += __shfl_down(acc, d);
    if ((tid & 63) == 0) sred[tid >> 6] = acc;
    __syncthreads();
    if (tid == 0) {
        float total = sred[0] + sred[1] + sred[2] + sred[3];
        if (label[n] != -100) atomicAdd(loss_sum, total);
    }
}

// ---------------------------------------------------------------------------
// Finalize: loss = loss_sum / n_non_ignore (0 if none).
// ---------------------------------------------------------------------------
__global__ __launch_bounds__(256)
void finalize_kernel(const float* __restrict__ loss_sum,
                     const int* __restrict__ label,
                     float* __restrict__ out)
{
    __shared__ int cred[4];
    int tid = threadIdx.x;
    int cnt = 0;
    for (int n = tid; n < N_TOK; n += 256) cnt += (label[n] != -100) ? 1 : 0;
    for (int d = 32; d; d >>= 1) cnt += __shfl_down(cnt, d);
    if ((tid & 63) == 0) cred[tid >> 6] = cnt;
    __syncthreads();
    if (tid == 0) {
        int c = cred[0] + cred[1] + cred[2] + cred[3];
        out[0] = (c > 0) ? (loss_sum[0] / (float)c) : 0.f;
    }
}

extern "C" void kernel_launch(void* const* d_in, const int* in_sizes, int n_in,
                              void* d_out, int out_size, void* d_ws, size_t ws_size,
                              hipStream_t stream) {
    const float* Xs    = (const float*)d_in[0];
    const float* Xt    = (const float*)d_in[1];
    const float* Ws    = (const float*)d_in[2];
    const float* Wt    = (const float*)d_in[3];
    const int*   label = (const int*)d_in[4];

    char* ws = (char*)d_ws;
    __hip_bfloat16* logits = (__hip_bfloat16*)ws;
    size_t logitsBytes = (size_t)2 * N_TOK * V_DIM * sizeof(__hip_bfloat16); // 262.1 MB
    float* loss_sum = (float*)(ws + logitsBytes);

    hipMemsetAsync(loss_sum, 0, sizeof(float), stream);

    gemm_logits_kernel<<<8000, 256, 0, stream>>>(Xs, Xt, Ws, Wt, logits);
    jsd_reduce_kernel<<<N_TOK, 256, 0, stream>>>(logits, label, loss_sum);
    finalize_kernel<<<1, 256, 0, stream>>>(loss_sum, label, (float*)d_out);
}